// Round 3
// baseline (1245.720 us; speedup 1.0000x reference)
//
#include <hip/hip_runtime.h>
#include <hip/hip_fp16.h>
#include <hip/hip_cooperative_groups.h>
#include <math.h>

namespace cg = cooperative_groups;

#define N 1024
#define H 256
#define L 512
#define NG 50
#define NI 3
#define B 16
#define NBINS 2048         // nearest-bin LUT over [0, CUT], sampled at centers
#define CUT 5.0f
#define BPB 16             // bins per table item (4 per wave, 1 MFMA tile)
#define TROWS (NBINS + 1)  // rows per table; row NBINS = zero sentinel
#define MATB 4             // atoms per mlp item
#define CAP 768            // max (padded) neighbors per atom
#define APAD 264           // padded LDS row (bf16) to break bank conflicts
#define KH 24              // fw1 rows staged per half in table phase

typedef __attribute__((ext_vector_type(8))) short bf16x8;
typedef __attribute__((ext_vector_type(4))) float f32x4;

// NOTE: param must NOT be named 'w' — it would capture the '.w' member token.
#define FMA4(A_, S_, V_) do { \
    (A_).x = fmaf((S_), (V_).x, (A_).x); (A_).y = fmaf((S_), (V_).y, (A_).y); \
    (A_).z = fmaf((S_), (V_).z, (A_).z); (A_).w = fmaf((S_), (V_).w, (A_).w); } while (0)

__device__ __forceinline__ float gelu_f(float x) {
    return 0.5f * x * (1.0f + erff(x * 0.70710678118654752f));
}
__device__ __forceinline__ unsigned short f2bf(float f) {
    unsigned u = __float_as_uint(f);
    unsigned r = (u + 0x7fffu + ((u >> 16) & 1u)) >> 16;   // RNE
    return (unsigned short)r;
}

// Phase-overlaid LDS. Max member: TableS = 24576+3584+8448 = 36608 B
// -> 4 blocks/CU (146 KB of 160 KB), the co-residency target.
struct SetupS { int cnt; int meta[CAP]; };
struct TableS { float w1[KH][H]; float rbf[BPB][56]; unsigned short ab[BPB][APAD]; };
struct PairS  { float part[4][H]; };
struct MlpS   { float at[H][MATB]; float gt[H][MATB]; float part[4][MATB][H]; };
struct HeadS  { float p[H]; float pw[4][H]; float g[H]; float p2[4][L]; float x[L]; float red[256]; };
union __align__(16) SharedU { SetupS su; TableS tb; PairS pr; MlpS ml; HeadS hd; };

// Single persistent cooperative kernel: setup -> table -> NI x (pair -> mlp)
// -> head, with grid.sync() between phases. Replaces 9 dispatch boundaries
// (~10 us each) with 8 in-kernel grid barriers (~2-4 us each).
__global__ void __launch_bounds__(256, 4) mega_k(
        const int* __restrict__ z, const float* __restrict__ pos,
        const float* __restrict__ emb,
        const float* __restrict__ fw1, const float* __restrict__ fb1,
        const float* __restrict__ fw2, const float* __restrict__ fb2,
        const float* __restrict__ aw1, const float* __restrict__ ab1,
        const float* __restrict__ aw2, const float* __restrict__ ab2,
        const float* __restrict__ pw1, const float* __restrict__ pb1,
        const float* __restrict__ pw2, const float* __restrict__ pb2,
        const float* __restrict__ ln_g, const float* __restrict__ ln_b,
        float* __restrict__ out,
        float* __restrict__ hbuf0, float* __restrict__ hbuf1,
        float* __restrict__ agg,
        __half* __restrict__ hhalf0, __half* __restrict__ hhalf1,
        __half* __restrict__ Wtb, int* __restrict__ meta,
        int* __restrict__ cnts, unsigned short* __restrict__ Bt) {
    cg::grid_group grid = cg::this_grid();
    __shared__ SharedU S;
    int tid = threadIdx.x;
    int wid = tid >> 6, lane = tid & 63;
    int c4 = lane * 4;

    // ---------------- Phase 0: setup (embed + neighbor lists + Bt) --------
    for (int item = blockIdx.x; item < N + NI * H; item += gridDim.x) {
        if (item >= N) {
            int blk = item - N;
            int l = blk / H, ch = blk % H;
            float v = fw2[((size_t)l * H + tid) * H + ch];
            Bt[((size_t)l * H + ch) * H + tid] = f2bf(v);
            if (tid == 0)
                Wtb[((size_t)l * TROWS + NBINS) * H + ch] = __float2half(0.f);
            continue;
        }
        int i = item;
        float v = emb[z[i] * H + tid];
        hbuf0[i * H + tid] = v;
        hhalf0[i * H + tid] = __float2half(v);

        if (tid == 0) S.su.cnt = 0;
        __syncthreads();
        float pix = pos[i * 3 + 0], piy = pos[i * 3 + 1], piz = pos[i * 3 + 2];
        const float invd = (float)NBINS / CUT;
        for (int r = 0; r < 4; ++r) {
            int j = tid + r * 256;
            float dx = pos[j * 3 + 0] - pix;
            float dy = pos[j * 3 + 1] - piy;
            float dz = pos[j * 3 + 2] - piz;
            float d = sqrtf(dx * dx + dy * dy + dz * dz);
            bool keep = (d < CUT && d > 1e-6f);
            unsigned long long mk = __ballot(keep);
            int base = 0;
            if (lane == 0) base = atomicAdd(&S.su.cnt, (int)__popcll(mk));
            base = __shfl(base, 0);
            if (keep) {
                int bin = (int)(d * invd);
                if (bin > NBINS - 1) bin = NBINS - 1;
                int off = (int)__popcll(mk & ((1ull << lane) - 1ull));
                S.su.meta[base + off] = j | (bin << 10);
            }
        }
        __syncthreads();
        int cnt = S.su.cnt;
        int pc = (cnt + 31) & ~31;         // mult of 32 -> stream len mult of 8
        for (int t = cnt + tid; t < pc; t += 256)
            S.su.meta[t] = i | (NBINS << 10);   // sentinel -> zero row
        __syncthreads();
        for (int t = tid; t < pc; t += 256)
            meta[(size_t)i * CAP + t] = S.su.meta[t];
        if (tid == 0) cnts[i] = pc;
    }
    __threadfence();
    grid.sync();

    // ---------------- Phase 1: filter tables (NI x 128 items) -------------
    for (int item = blockIdx.x; item < NI * (NBINS / BPB); item += gridDim.x) {
        int layer = item / (NBINS / BPB);
        int blk = item % (NBINS / BPB);
        int b0 = blk * BPB;
        int ub = wid * 4;
        const float* lfw1 = fw1 + layer * NG * H;
        __half* lWt = Wtb + (size_t)layer * TROWS * H;
        const float delta = CUT / (float)NBINS;

        for (int idx = tid; idx < BPB * NG; idx += 256) {
            int u = idx & 15, k = idx >> 4;
            float d = ((float)(b0 + u) + 0.5f) * delta;   // bin CENTER
            float t = d - (float)k * (CUT / 49.0f);
            S.tb.rbf[u][k] = expf(t * t * -200.0f);       // -1/(2*0.05^2)
        }
        // K-tail rows (48,49) straight from L2 — issued early, used at end
        float4 q48 = *(const float4*)(lfw1 + 48 * H + c4);
        float4 q49 = *(const float4*)(lfw1 + 49 * H + c4);

        float4 acc1[4];
        #pragma unroll
        for (int u = 0; u < 4; ++u) acc1[u] = make_float4(0.f, 0.f, 0.f, 0.f);
        #pragma unroll
        for (int hf = 0; hf < 2; ++hf) {
            int kb = hf * KH;
            if (hf) __syncthreads();       // protect w1 overwrite
            for (int idx = tid; idx < KH * (H / 4); idx += 256) {
                int k = idx >> 6, c = (idx & 63) * 4;
                *(float4*)&S.tb.w1[k][c] = *(const float4*)(lfw1 + (kb + k) * H + c);
            }
            __syncthreads();
            for (int kq = 0; kq < KH / 4; ++kq) {
                int k = kq * 4;
                float4 r0 = *(const float4*)&S.tb.rbf[ub + 0][kb + k];
                float4 r1 = *(const float4*)&S.tb.rbf[ub + 1][kb + k];
                float4 r2 = *(const float4*)&S.tb.rbf[ub + 2][kb + k];
                float4 r3 = *(const float4*)&S.tb.rbf[ub + 3][kb + k];
                float4 q0 = *(const float4*)&S.tb.w1[k + 0][c4];
                float4 q1 = *(const float4*)&S.tb.w1[k + 1][c4];
                float4 q2 = *(const float4*)&S.tb.w1[k + 2][c4];
                float4 q3 = *(const float4*)&S.tb.w1[k + 3][c4];
                FMA4(acc1[0], r0.x, q0); FMA4(acc1[0], r0.y, q1);
                FMA4(acc1[0], r0.z, q2); FMA4(acc1[0], r0.w, q3);
                FMA4(acc1[1], r1.x, q0); FMA4(acc1[1], r1.y, q1);
                FMA4(acc1[1], r1.z, q2); FMA4(acc1[1], r1.w, q3);
                FMA4(acc1[2], r2.x, q0); FMA4(acc1[2], r2.y, q1);
                FMA4(acc1[2], r2.z, q2); FMA4(acc1[2], r2.w, q3);
                FMA4(acc1[3], r3.x, q0); FMA4(acc1[3], r3.y, q1);
                FMA4(acc1[3], r3.z, q2); FMA4(acc1[3], r3.w, q3);
            }
        }
        #pragma unroll
        for (int u = 0; u < 4; ++u) {
            FMA4(acc1[u], S.tb.rbf[ub + u][48], q48);
            FMA4(acc1[u], S.tb.rbf[ub + u][49], q49);
        }
        float4 b1 = *(const float4*)(fb1 + layer * H + c4);
        #pragma unroll
        for (int u = 0; u < 4; ++u) {
            ushort4 g;
            g.x = f2bf(gelu_f(acc1[u].x + b1.x));
            g.y = f2bf(gelu_f(acc1[u].y + b1.y));
            g.z = f2bf(gelu_f(acc1[u].z + b1.z));
            g.w = f2bf(gelu_f(acc1[u].w + b1.w));
            *(ushort4*)&S.tb.ab[ub + u][c4] = g;
        }
        __syncthreads();

        // layer 2: MFMA. One 16-bin tile; wave wid covers ch-tiles 4w..4w+3.
        int m = lane & 15;
        int quad = lane >> 4;
        bf16x8 afr[8];
        #pragma unroll
        for (int c = 0; c < 8; ++c)
            afr[c] = *(const bf16x8*)&S.tb.ab[m][c * 32 + quad * 8];
        #pragma unroll
        for (int ct = 0; ct < 4; ++ct) {
            int chn = (wid * 4 + ct) * 16 + m;
            const bf16x8* Bv = (const bf16x8*)(Bt + ((size_t)layer * H + chn) * H);
            f32x4 acc = {0.f, 0.f, 0.f, 0.f};
            #pragma unroll
            for (int c = 0; c < 8; ++c)
                acc = __builtin_amdgcn_mfma_f32_16x16x32_bf16(afr[c], Bv[c * 4 + quad],
                                                              acc, 0, 0, 0);
            float bias = fb2[layer * H + chn];
            #pragma unroll
            for (int r = 0; r < 4; ++r) {
                int bin = b0 + quad * 4 + r;
                lWt[(size_t)bin * H + chn] = __float2half(acc[r] + bias);
            }
        }
    }
    __threadfence();
    grid.sync();

    // ---------------- NI x (pair -> mlp) ----------------------------------
    const float* hi = hbuf0;  float* ho = hbuf1;
    const __half* hfi = hhalf0; __half* hfo = hhalf1;
    for (int itn = 0; itn < NI; ++itn) {
        const __half* Wt = Wtb + (size_t)itn * TROWS * H;
        const float* aw1i = aw1 + itn * H * H;
        const float* ab1i = ab1 + itn * H;
        const float* aw2i = aw2 + itn * H * H;
        const float* ab2i = ab2 + itn * H;

        // pair: 1 block per atom, 4 streams (waves), 8-wide x 2-deep pipeline
        for (int i = blockIdx.x; i < N; i += gridDim.x) {
            int pc = cnts[i];
            int len = pc >> 2;             // per-stream, multiple of 8
            int chunks = len >> 3;         // 8-neighbor chunks
            int sbase = __builtin_amdgcn_readfirstlane(wid * len);
            const int* mptr = meta + (size_t)i * CAP + sbase;
            const char* WtB = (const char*)Wt;
            const char* hhB = (const char*)hfi;
            int choffB = lane * 8;         // 4 fp16 = 8 B per lane

            float4 acc = make_float4(0.f, 0.f, 0.f, 0.f);
            uint2 wA[8], hA8[8], wB[8], hB8[8];
            int4 mA0, mA1, mB0, mB1;

            auto ld8 = [&](int c, int4& ma, int4& mb) {
                ma = *(const int4*)(mptr + c * 8);      // uniform -> s_load
                mb = *(const int4*)(mptr + c * 8 + 4);
            };
            auto one = [&](int p, uint2& wr, uint2& hr) {
                p = __builtin_amdgcn_readfirstlane(p);
                int j = p & 1023;
                int bin = p >> 10;
                wr = *(const uint2*)(WtB + (((unsigned)bin << 9) | (unsigned)choffB));
                hr = *(const uint2*)(hhB + (((unsigned)j << 9) | (unsigned)choffB));
            };
            auto issue8 = [&](const int4& ma, const int4& mb,
                              uint2 (&wr)[8], uint2 (&hr)[8]) {
                one(ma.x, wr[0], hr[0]); one(ma.y, wr[1], hr[1]);
                one(ma.z, wr[2], hr[2]); one(ma.w, wr[3], hr[3]);
                one(mb.x, wr[4], hr[4]); one(mb.y, wr[5], hr[5]);
                one(mb.z, wr[6], hr[6]); one(mb.w, wr[7], hr[7]);
            };
            auto consume8 = [&](uint2 (&wr)[8], uint2 (&hr)[8]) {
                #pragma unroll
                for (int u = 0; u < 8; ++u) {
                    __half2 w01 = *(__half2*)&wr[u].x;
                    __half2 w23 = *(__half2*)&wr[u].y;
                    __half2 h01 = *(__half2*)&hr[u].x;
                    __half2 h23 = *(__half2*)&hr[u].y;
                    acc.x += __half2float(w01.x) * __half2float(h01.x);
                    acc.y += __half2float(w01.y) * __half2float(h01.y);
                    acc.z += __half2float(w23.x) * __half2float(h23.x);
                    acc.w += __half2float(w23.y) * __half2float(h23.y);
                }
            };

            if (chunks > 0) { ld8(0, mA0, mA1); issue8(mA0, mA1, wA, hA8); }
            if (chunks > 1) { ld8(1, mB0, mB1); issue8(mB0, mB1, wB, hB8); }
            for (int c = 0; c < chunks; c += 2) {
                consume8(wA, hA8);
                if (c + 2 < chunks) { ld8(c + 2, mA0, mA1); issue8(mA0, mA1, wA, hA8); }
                if (c + 1 < chunks) {
                    consume8(wB, hB8);
                    if (c + 3 < chunks) { ld8(c + 3, mB0, mB1); issue8(mB0, mB1, wB, hB8); }
                }
            }
            *(float4*)&S.pr.part[wid][c4] = acc;
            __syncthreads();
            agg[(size_t)i * H + tid] = S.pr.part[0][tid] + S.pr.part[1][tid]
                                     + S.pr.part[2][tid] + S.pr.part[3][tid];
            __syncthreads();
        }
        __threadfence();
        grid.sync();

        // mlp: MATB atoms per item, 4 waves split K in quarters
        for (int it2 = blockIdx.x; it2 < N / MATB; it2 += gridDim.x) {
            int i0 = it2 * MATB;
            #pragma unroll
            for (int r = 0; r < MATB; ++r)
                S.ml.at[tid][r] = agg[(size_t)(i0 + r) * H + tid];
            __syncthreads();

            int k0 = wid * 64;
            float4 acc[MATB];
            #pragma unroll
            for (int a = 0; a < MATB; ++a) acc[a] = make_float4(0.f, 0.f, 0.f, 0.f);
            #pragma unroll 8
            for (int k = 0; k < 64; ++k) {
                float4 q = *(const float4*)(aw1i + (k0 + k) * H + c4);
                float4 act = *(const float4*)&S.ml.at[k0 + k][0];
                FMA4(acc[0], act.x, q); FMA4(acc[1], act.y, q);
                FMA4(acc[2], act.z, q); FMA4(acc[3], act.w, q);
            }
            #pragma unroll
            for (int a = 0; a < MATB; ++a)
                *(float4*)&S.ml.part[wid][a][c4] = acc[a];
            __syncthreads();
            {
                float b1v = ab1i[tid];
                float g[MATB];
                #pragma unroll
                for (int a = 0; a < MATB; ++a) {
                    float v = b1v;
                    #pragma unroll
                    for (int s = 0; s < 4; ++s) v += S.ml.part[s][a][tid];
                    g[a] = gelu_f(v);
                }
                *(float4*)&S.ml.gt[tid][0] = make_float4(g[0], g[1], g[2], g[3]);
            }
            __syncthreads();
            #pragma unroll
            for (int a = 0; a < MATB; ++a) acc[a] = make_float4(0.f, 0.f, 0.f, 0.f);
            #pragma unroll 8
            for (int k = 0; k < 64; ++k) {
                float4 q = *(const float4*)(aw2i + (k0 + k) * H + c4);
                float4 act = *(const float4*)&S.ml.gt[k0 + k][0];
                FMA4(acc[0], act.x, q); FMA4(acc[1], act.y, q);
                FMA4(acc[2], act.z, q); FMA4(acc[3], act.w, q);
            }
            #pragma unroll
            for (int a = 0; a < MATB; ++a)
                *(float4*)&S.ml.part[wid][a][c4] = acc[a];
            __syncthreads();
            {
                float b2v = ab2i[tid];
                #pragma unroll
                for (int a = 0; a < MATB; ++a) {
                    float v = b2v;
                    #pragma unroll
                    for (int s = 0; s < 4; ++s) v += S.ml.part[s][a][tid];
                    float hv = hi[(size_t)(i0 + a) * H + tid] + v;
                    ho[(size_t)(i0 + a) * H + tid] = hv;
                    hfo[(size_t)(i0 + a) * H + tid] = __float2half(hv);
                }
            }
            __syncthreads();
        }
        __threadfence();
        grid.sync();

        const float* t1 = hi; hi = ho; ho = (float*)t1;
        const __half* t2 = hfi; hfi = hfo; hfo = (__half*)t2;
    }

    // ---------------- head: 16 molecule items ----------------------------
    for (int b = blockIdx.x; b < B; b += gridDim.x) {
        float4 p = make_float4(0.f, 0.f, 0.f, 0.f);
        #pragma unroll 4
        for (int a = 0; a < 16; ++a) {
            float4 hv = *(const float4*)(hi + (size_t)(b * 64 + wid * 16 + a) * H + c4);
            p.x += hv.x; p.y += hv.y; p.z += hv.z; p.w += hv.w;
        }
        *(float4*)&S.hd.pw[wid][c4] = p;
        __syncthreads();
        S.hd.p[tid] = S.hd.pw[0][tid] + S.hd.pw[1][tid] + S.hd.pw[2][tid] + S.hd.pw[3][tid];
        __syncthreads();

        int k0 = wid * 64;
        float4 acc = make_float4(0.f, 0.f, 0.f, 0.f);
        #pragma unroll 8
        for (int k = 0; k < 64; ++k) {
            float4 q = *(const float4*)(pw1 + (k0 + k) * H + c4);
            float s = S.hd.p[k0 + k];
            FMA4(acc, s, q);
        }
        *(float4*)&S.hd.pw[wid][c4] = acc;
        __syncthreads();
        S.hd.g[tid] = gelu_f(pb1[tid] + S.hd.pw[0][tid] + S.hd.pw[1][tid]
                             + S.hd.pw[2][tid] + S.hd.pw[3][tid]);
        __syncthreads();

        float4 a0 = make_float4(0.f, 0.f, 0.f, 0.f);
        float4 a1 = make_float4(0.f, 0.f, 0.f, 0.f);
        #pragma unroll 4
        for (int k = 0; k < 64; ++k) {
            float s = S.hd.g[k0 + k];
            float4 q0 = *(const float4*)(pw2 + (k0 + k) * L + lane * 8);
            float4 q1 = *(const float4*)(pw2 + (k0 + k) * L + lane * 8 + 4);
            FMA4(a0, s, q0);
            FMA4(a1, s, q1);
        }
        *(float4*)&S.hd.p2[wid][lane * 8] = a0;
        *(float4*)&S.hd.p2[wid][lane * 8 + 4] = a1;
        __syncthreads();
        for (int r = 0; r < 2; ++r) {
            int l = tid + r * 256;
            S.hd.x[l] = pb2[l] + S.hd.p2[0][l] + S.hd.p2[1][l]
                      + S.hd.p2[2][l] + S.hd.p2[3][l];
        }
        __syncthreads();

        S.hd.red[tid] = S.hd.x[tid] + S.hd.x[tid + 256];
        __syncthreads();
        for (int off = 128; off > 0; off >>= 1) {
            if (tid < off) S.hd.red[tid] += S.hd.red[tid + off];
            __syncthreads();
        }
        float mu = S.hd.red[0] / (float)L;
        __syncthreads();
        float d0 = S.hd.x[tid] - mu, d1 = S.hd.x[tid + 256] - mu;
        S.hd.red[tid] = d0 * d0 + d1 * d1;
        __syncthreads();
        for (int off = 128; off > 0; off >>= 1) {
            if (tid < off) S.hd.red[tid] += S.hd.red[tid + off];
            __syncthreads();
        }
        float var = S.hd.red[0] / (float)L;
        float rstd = rsqrtf(var + 1e-5f);
        for (int r = 0; r < 2; ++r) {
            int l = tid + r * 256;
            out[b * L + l] = (S.hd.x[l] - mu) * rstd * ln_g[l] + ln_b[l];
        }
        __syncthreads();
    }
}

extern "C" void kernel_launch(void* const* d_in, const int* in_sizes, int n_in,
                              void* d_out, int out_size, void* d_ws, size_t ws_size,
                              hipStream_t stream) {
    const int*   z    = (const int*)d_in[0];
    const float* pos  = (const float*)d_in[1];
    // d_in[2] = batch: fixed arange//64 layout, handled implicitly in head
    const float* emb  = (const float*)d_in[3];
    const float* fw1  = (const float*)d_in[4];
    const float* fb1  = (const float*)d_in[5];
    const float* fw2  = (const float*)d_in[6];
    const float* fb2  = (const float*)d_in[7];
    const float* aw1  = (const float*)d_in[8];
    const float* ab1  = (const float*)d_in[9];
    const float* aw2  = (const float*)d_in[10];
    const float* ab2  = (const float*)d_in[11];
    const float* pw1  = (const float*)d_in[12];
    const float* pb1  = (const float*)d_in[13];
    const float* pw2  = (const float*)d_in[14];
    const float* pb2  = (const float*)d_in[15];
    const float* ln_g = (const float*)d_in[16];
    const float* ln_b = (const float*)d_in[17];
    float* out = (float*)d_out;

    float* hbuf0 = (float*)d_ws;                        // [N][H] fp32
    float* hbuf1 = hbuf0 + N * H;                       // [N][H] fp32
    float* agg   = hbuf1 + N * H;                       // [N][H] fp32 (+spare)
    __half* hhalf0 = (__half*)(agg + 2 * N * H);        // [N][H] fp16
    __half* hhalf1 = hhalf0 + N * H;                    // [N][H] fp16
    __half* Wtb  = hhalf1 + N * H;                      // [NI][TROWS][H] fp16
    int* meta = (int*)(Wtb + (size_t)NI * TROWS * H);   // [N][CAP]
    int* cnts = meta + (size_t)N * CAP;                 // [N]
    unsigned short* Bt = (unsigned short*)(cnts + N);   // [NI][H][H] bf16

    static int occ = 0;
    if (occ == 0) {
        if (hipOccupancyMaxActiveBlocksPerMultiprocessor(&occ, mega_k, 256, 0)
                != hipSuccess || occ < 1)
            occ = 3;                                    // conservative fallback
        if (occ > 4) occ = 4;
    }
    int nblk = occ * 256;                               // 256 CUs on MI355X
    if (nblk > 1024) nblk = 1024;

    void* args[] = { &z, &pos, &emb, &fw1, &fb1, &fw2, &fb2, &aw1, &ab1,
                     &aw2, &ab2, &pw1, &pb1, &pw2, &pb2, &ln_g, &ln_b, &out,
                     &hbuf0, &hbuf1, &agg, &hhalf0, &hhalf1, &Wtb, &meta,
                     &cnts, &Bt };
    hipLaunchCooperativeKernel(mega_k, dim3(nblk), dim3(256), args, 0, stream);
}

// Round 5
// 704.447 us; speedup vs baseline: 1.7684x; 1.7684x over previous
//
#include <hip/hip_runtime.h>
#include <hip/hip_fp16.h>
#include <hip/hip_cooperative_groups.h>
#include <math.h>

namespace cg = cooperative_groups;

#define N 1024
#define H 256
#define L 512
#define NG 50
#define NI 3
#define B 16
#define NBINS 2048         // nearest-bin LUT over [0, CUT], sampled at centers
#define CUT 5.0f
#define BPB 16             // bins per table item (4 per wave, 1 MFMA tile)
#define TROWS (NBINS + 1)  // rows per table; row NBINS = zero sentinel
#define MATB 4             // atoms per mlp item
#define CAP 768            // max (padded) neighbors per atom
#define APAD 264           // padded LDS row (bf16) to break bank conflicts
#define KH 24              // fw1 rows staged per half in table phase

typedef __attribute__((ext_vector_type(8))) short bf16x8;
typedef __attribute__((ext_vector_type(4))) float f32x4;

// NOTE: param must NOT be named 'w' — it would capture the '.w' member token.
#define FMA4(A_, S_, V_) do { \
    (A_).x = fmaf((S_), (V_).x, (A_).x); (A_).y = fmaf((S_), (V_).y, (A_).y); \
    (A_).z = fmaf((S_), (V_).z, (A_).z); (A_).w = fmaf((S_), (V_).w, (A_).w); } while (0)

__device__ __forceinline__ float gelu_f(float x) {
    return 0.5f * x * (1.0f + erff(x * 0.70710678118654752f));
}
__device__ __forceinline__ unsigned short f2bf(float f) {
    unsigned u = __float_as_uint(f);
    unsigned r = (u + 0x7fffu + ((u >> 16) & 1u)) >> 16;   // RNE
    return (unsigned short)r;
}

// ======================= split kernels (fallback path) =====================
__global__ void __launch_bounds__(256) setup_k(
        const int* __restrict__ z, const float* __restrict__ emb,
        const float* __restrict__ pos, float* __restrict__ h,
        __half* __restrict__ hhf, int* __restrict__ meta,
        int* __restrict__ cnts, const float* __restrict__ fw2,
        unsigned short* __restrict__ Bt, __half* __restrict__ Wtb) {
    int tid = threadIdx.x;
    if (blockIdx.x >= N) {
        int blk = blockIdx.x - N;
        int l = blk / H, ch = blk % H;
        float v = fw2[((size_t)l * H + tid) * H + ch];
        Bt[((size_t)l * H + ch) * H + tid] = f2bf(v);
        if (tid == 0)
            Wtb[((size_t)l * TROWS + NBINS) * H + ch] = __float2half(0.f);
        return;
    }
    int i = blockIdx.x;
    float v = emb[z[i] * H + tid];
    h[i * H + tid] = v;
    hhf[i * H + tid] = __float2half(v);

    __shared__ int sCnt;
    __shared__ int sMeta[CAP];
    if (tid == 0) sCnt = 0;
    __syncthreads();
    float pix = pos[i * 3 + 0], piy = pos[i * 3 + 1], piz = pos[i * 3 + 2];
    const float invd = (float)NBINS / CUT;
    int lane = tid & 63;
    for (int r = 0; r < 4; ++r) {
        int j = tid + r * 256;
        float dx = pos[j * 3 + 0] - pix;
        float dy = pos[j * 3 + 1] - piy;
        float dz = pos[j * 3 + 2] - piz;
        float d = sqrtf(dx * dx + dy * dy + dz * dz);
        bool keep = (d < CUT && d > 1e-6f);
        unsigned long long mk = __ballot(keep);
        int base = 0;
        if (lane == 0) base = atomicAdd(&sCnt, (int)__popcll(mk));
        base = __shfl(base, 0);
        if (keep) {
            int bin = (int)(d * invd);
            if (bin > NBINS - 1) bin = NBINS - 1;
            int off = (int)__popcll(mk & ((1ull << lane) - 1ull));
            sMeta[base + off] = j | (bin << 10);
        }
    }
    __syncthreads();
    int cnt = sCnt;
    int pc = (cnt + 31) & ~31;
    for (int t = cnt + tid; t < pc; t += 256)
        sMeta[t] = i | (NBINS << 10);
    __syncthreads();
    for (int t = tid; t < pc; t += 256)
        meta[(size_t)i * CAP + t] = sMeta[t];
    if (tid == 0) cnts[i] = pc;
}

__global__ void __launch_bounds__(256) table_k(
        const float* __restrict__ fw1, const float* __restrict__ fb1,
        const unsigned short* __restrict__ Bt, const float* __restrict__ fb2,
        __half* __restrict__ Wtb) {
    const int bpl = NBINS / BPB;
    int layer = blockIdx.x / bpl;
    int blk = blockIdx.x % bpl;
    int b0 = blk * BPB;
    int tid = threadIdx.x;
    int wid = tid >> 6, lane = tid & 63;
    int c4 = lane * 4;
    int ub = wid * 4;
    const float* lfw1 = fw1 + layer * NG * H;
    __half* lWt = Wtb + (size_t)layer * TROWS * H;

    __shared__ __align__(16) float sW1[NG][H];
    __shared__ __align__(16) float sRbf[BPB][56];
    __shared__ __align__(16) unsigned short sAb[BPB][APAD];
    const float delta = CUT / (float)NBINS;
    for (int idx = tid; idx < NG * (H / 4); idx += 256) {
        int k = idx >> 6;
        int c = (idx & 63) * 4;
        *(float4*)&sW1[k][c] = *(const float4*)(lfw1 + k * H + c);
    }
    for (int idx = tid; idx < BPB * NG; idx += 256) {
        int u = idx & 15;
        int k = idx >> 4;
        float d = ((float)(b0 + u) + 0.5f) * delta;
        float t = d - (float)k * (CUT / 49.0f);
        sRbf[u][k] = expf(t * t * -200.0f);
    }
    __syncthreads();

    float4 acc1[4];
    #pragma unroll
    for (int u = 0; u < 4; ++u) acc1[u] = make_float4(0.f, 0.f, 0.f, 0.f);
    for (int kq = 0; kq < 12; ++kq) {
        int k = kq * 4;
        float4 r0 = *(const float4*)&sRbf[ub + 0][k];
        float4 r1 = *(const float4*)&sRbf[ub + 1][k];
        float4 r2 = *(const float4*)&sRbf[ub + 2][k];
        float4 r3 = *(const float4*)&sRbf[ub + 3][k];
        float4 q0 = *(const float4*)&sW1[k + 0][c4];
        float4 q1 = *(const float4*)&sW1[k + 1][c4];
        float4 q2 = *(const float4*)&sW1[k + 2][c4];
        float4 q3 = *(const float4*)&sW1[k + 3][c4];
        FMA4(acc1[0], r0.x, q0); FMA4(acc1[0], r0.y, q1);
        FMA4(acc1[0], r0.z, q2); FMA4(acc1[0], r0.w, q3);
        FMA4(acc1[1], r1.x, q0); FMA4(acc1[1], r1.y, q1);
        FMA4(acc1[1], r1.z, q2); FMA4(acc1[1], r1.w, q3);
        FMA4(acc1[2], r2.x, q0); FMA4(acc1[2], r2.y, q1);
        FMA4(acc1[2], r2.z, q2); FMA4(acc1[2], r2.w, q3);
        FMA4(acc1[3], r3.x, q0); FMA4(acc1[3], r3.y, q1);
        FMA4(acc1[3], r3.z, q2); FMA4(acc1[3], r3.w, q3);
    }
    for (int k = 48; k < NG; ++k) {
        float4 q = *(const float4*)&sW1[k][c4];
        #pragma unroll
        for (int u = 0; u < 4; ++u) FMA4(acc1[u], sRbf[ub + u][k], q);
    }
    float4 b1 = *(const float4*)(fb1 + layer * H + c4);
    #pragma unroll
    for (int u = 0; u < 4; ++u) {
        ushort4 g;
        g.x = f2bf(gelu_f(acc1[u].x + b1.x));
        g.y = f2bf(gelu_f(acc1[u].y + b1.y));
        g.z = f2bf(gelu_f(acc1[u].z + b1.z));
        g.w = f2bf(gelu_f(acc1[u].w + b1.w));
        *(ushort4*)&sAb[ub + u][c4] = g;
    }
    __syncthreads();

    int m = lane & 15;
    int quad = lane >> 4;
    bf16x8 afr[8];
    #pragma unroll
    for (int c = 0; c < 8; ++c)
        afr[c] = *(const bf16x8*)&sAb[m][c * 32 + quad * 8];
    #pragma unroll
    for (int ct = 0; ct < 4; ++ct) {
        int chn = (wid * 4 + ct) * 16 + m;
        const bf16x8* Bv = (const bf16x8*)(Bt + ((size_t)layer * H + chn) * H);
        f32x4 acc = {0.f, 0.f, 0.f, 0.f};
        #pragma unroll
        for (int c = 0; c < 8; ++c)
            acc = __builtin_amdgcn_mfma_f32_16x16x32_bf16(afr[c], Bv[c * 4 + quad],
                                                          acc, 0, 0, 0);
        float bias = fb2[layer * H + chn];
        #pragma unroll
        for (int r = 0; r < 4; ++r) {
            int bin = b0 + quad * 4 + r;
            lWt[(size_t)bin * H + chn] = __float2half(acc[r] + bias);
        }
    }
}

__global__ void __launch_bounds__(256) pair_k(
    const __half* __restrict__ hhf, const __half* __restrict__ Wt,
    const int* __restrict__ gmeta, const int* __restrict__ cnts,
    float* __restrict__ aggP) {
    int tid = threadIdx.x;
    int wid = tid >> 6, lane = tid & 63;
    int c4 = lane * 4;
    int i = blockIdx.x >> 1;
    int half = blockIdx.x & 1;
    int stream = half * 4 + wid;

    __shared__ __align__(16) float sPart[4][H];

    int pc = cnts[i];
    int len = pc >> 3;
    int chunks = len >> 2;
    int sbase = __builtin_amdgcn_readfirstlane(stream * len);
    const int* mptr = gmeta + (size_t)i * CAP + sbase;
    const char* WtB = (const char*)Wt;
    const char* hhB = (const char*)hhf;
    int choffB = lane * 8;

    float4 acc = make_float4(0.f, 0.f, 0.f, 0.f);
    int4 mA, mB;
    uint2 wA[4], hA[4], wB[4], hB[4];

    auto ldmeta = [&](int c) -> int4 {
        return *(const int4*)(mptr + c * 4);
    };
    auto one = [&](int p, uint2& wr, uint2& hr) {
        p = __builtin_amdgcn_readfirstlane(p);
        int j = p & 1023;
        int bin = p >> 10;
        wr = *(const uint2*)(WtB + (((unsigned)bin << 9) | (unsigned)choffB));
        hr = *(const uint2*)(hhB + (((unsigned)j << 9) | (unsigned)choffB));
    };
    auto issueD = [&](const int4& m4, uint2 (&wr)[4], uint2 (&hr)[4]) {
        one(m4.x, wr[0], hr[0]); one(m4.y, wr[1], hr[1]);
        one(m4.z, wr[2], hr[2]); one(m4.w, wr[3], hr[3]);
    };
    auto consume = [&](uint2 (&wr)[4], uint2 (&hr)[4]) {
        #pragma unroll
        for (int u = 0; u < 4; ++u) {
            __half2 w01 = *(__half2*)&wr[u].x;
            __half2 w23 = *(__half2*)&wr[u].y;
            __half2 h01 = *(__half2*)&hr[u].x;
            __half2 h23 = *(__half2*)&hr[u].y;
            acc.x += __half2float(w01.x) * __half2float(h01.x);
            acc.y += __half2float(w01.y) * __half2float(h01.y);
            acc.z += __half2float(w23.x) * __half2float(h23.x);
            acc.w += __half2float(w23.y) * __half2float(h23.y);
        }
    };

    if (chunks > 0) {
        mA = ldmeta(0);
        if (chunks > 1) mB = ldmeta(1);
        issueD(mA, wA, hA);
        for (int c = 0; c < chunks; c += 2) {
            if (c + 2 < chunks) mA = ldmeta(c + 2);
            if (c + 1 < chunks) issueD(mB, wB, hB);
            consume(wA, hA);
            if (c + 3 < chunks) mB = ldmeta(c + 3);
            if (c + 2 < chunks) issueD(mA, wA, hA);
            if (c + 1 < chunks) consume(wB, hB);
        }
    }
    *(float4*)&sPart[wid][c4] = acc;
    __syncthreads();
    aggP[((size_t)half * N + i) * H + tid] =
        sPart[0][tid] + sPart[1][tid] + sPart[2][tid] + sPart[3][tid];
}

__global__ void __launch_bounds__(512) mlp_k(
    const float* __restrict__ aggP, const float* __restrict__ hin,
    const float* __restrict__ aw1, const float* __restrict__ ab1,
    const float* __restrict__ aw2, const float* __restrict__ ab2,
    float* __restrict__ hout, __half* __restrict__ hhf_out) {
    int tid = threadIdx.x;
    int wid = tid >> 6, lane = tid & 63;
    int c4 = lane * 4;
    int i0 = blockIdx.x * MATB;
    __shared__ __align__(16) float sAT[H][MATB];
    __shared__ __align__(16) float sGT[H][MATB];
    __shared__ __align__(16) float sPart[8][MATB][H];

    if (tid < H) {
        #pragma unroll
        for (int r = 0; r < MATB; ++r)
            sAT[tid][r] = aggP[(size_t)(i0 + r) * H + tid]
                        + aggP[((size_t)N + i0 + r) * H + tid];
    }
    __syncthreads();

    int k0 = wid * 32;
    float4 acc[MATB];
    #pragma unroll
    for (int a = 0; a < MATB; ++a) acc[a] = make_float4(0.f, 0.f, 0.f, 0.f);
    #pragma unroll 8
    for (int k = 0; k < 32; ++k) {
        float4 q = *(const float4*)(aw1 + (k0 + k) * H + c4);
        float4 act = *(const float4*)&sAT[k0 + k][0];
        FMA4(acc[0], act.x, q); FMA4(acc[1], act.y, q);
        FMA4(acc[2], act.z, q); FMA4(acc[3], act.w, q);
    }
    #pragma unroll
    for (int a = 0; a < MATB; ++a)
        *(float4*)&sPart[wid][a][c4] = acc[a];
    __syncthreads();
    if (tid < H) {
        float b1 = ab1[tid];
        float g[MATB];
        #pragma unroll
        for (int a = 0; a < MATB; ++a) {
            float v = b1;
            #pragma unroll
            for (int s = 0; s < 8; ++s) v += sPart[s][a][tid];
            g[a] = gelu_f(v);
        }
        *(float4*)&sGT[tid][0] = make_float4(g[0], g[1], g[2], g[3]);
    }
    __syncthreads();
    #pragma unroll
    for (int a = 0; a < MATB; ++a) acc[a] = make_float4(0.f, 0.f, 0.f, 0.f);
    #pragma unroll 8
    for (int k = 0; k < 32; ++k) {
        float4 q = *(const float4*)(aw2 + (k0 + k) * H + c4);
        float4 act = *(const float4*)&sGT[k0 + k][0];
        FMA4(acc[0], act.x, q); FMA4(acc[1], act.y, q);
        FMA4(acc[2], act.z, q); FMA4(acc[3], act.w, q);
    }
    #pragma unroll
    for (int a = 0; a < MATB; ++a)
        *(float4*)&sPart[wid][a][c4] = acc[a];
    __syncthreads();
    if (tid < H) {
        float b2 = ab2[tid];
        #pragma unroll
        for (int a = 0; a < MATB; ++a) {
            float v = b2;
            #pragma unroll
            for (int s = 0; s < 8; ++s) v += sPart[s][a][tid];
            float hv = hin[(i0 + a) * H + tid] + v;
            hout[(i0 + a) * H + tid] = hv;
            hhf_out[(i0 + a) * H + tid] = __float2half(hv);
        }
    }
}

__global__ void __launch_bounds__(256) head_k(
        const float* __restrict__ h,
        const float* __restrict__ pw1, const float* __restrict__ pb1,
        const float* __restrict__ pw2, const float* __restrict__ pb2,
        const float* __restrict__ ln_g, const float* __restrict__ ln_b,
        float* __restrict__ out) {
    int b = blockIdx.x, tid = threadIdx.x;
    int wid = tid >> 6, lane = tid & 63;
    int c4 = lane * 4;
    __shared__ float sP[H];
    __shared__ __align__(16) float sPw[4][H];
    __shared__ float sG[H];
    __shared__ __align__(16) float sP2[4][L];
    __shared__ float sX[L];
    __shared__ float sRed[256];

    float4 p = make_float4(0.f, 0.f, 0.f, 0.f);
    #pragma unroll 4
    for (int a = 0; a < 16; ++a) {
        float4 hv = *(const float4*)(h + (b * 64 + wid * 16 + a) * H + c4);
        p.x += hv.x; p.y += hv.y; p.z += hv.z; p.w += hv.w;
    }
    *(float4*)&sPw[wid][c4] = p;
    __syncthreads();
    sP[tid] = sPw[0][tid] + sPw[1][tid] + sPw[2][tid] + sPw[3][tid];
    __syncthreads();

    int k0 = wid * 64;
    float4 acc = make_float4(0.f, 0.f, 0.f, 0.f);
    #pragma unroll 8
    for (int k = 0; k < 64; ++k) {
        float4 q = *(const float4*)(pw1 + (k0 + k) * H + c4);
        float s = sP[k0 + k];
        FMA4(acc, s, q);
    }
    *(float4*)&sPw[wid][c4] = acc;
    __syncthreads();
    sG[tid] = gelu_f(pb1[tid] + sPw[0][tid] + sPw[1][tid] + sPw[2][tid] + sPw[3][tid]);
    __syncthreads();

    float4 a0 = make_float4(0.f, 0.f, 0.f, 0.f);
    float4 a1 = make_float4(0.f, 0.f, 0.f, 0.f);
    #pragma unroll 4
    for (int k = 0; k < 64; ++k) {
        float s = sG[k0 + k];
        float4 q0 = *(const float4*)(pw2 + (k0 + k) * L + lane * 8);
        float4 q1 = *(const float4*)(pw2 + (k0 + k) * L + lane * 8 + 4);
        FMA4(a0, s, q0);
        FMA4(a1, s, q1);
    }
    *(float4*)&sP2[wid][lane * 8] = a0;
    *(float4*)&sP2[wid][lane * 8 + 4] = a1;
    __syncthreads();
    for (int r = 0; r < 2; ++r) {
        int l = tid + r * 256;
        sX[l] = pb2[l] + sP2[0][l] + sP2[1][l] + sP2[2][l] + sP2[3][l];
    }
    __syncthreads();

    sRed[tid] = sX[tid] + sX[tid + 256];
    __syncthreads();
    for (int off = 128; off > 0; off >>= 1) {
        if (tid < off) sRed[tid] += sRed[tid + off];
        __syncthreads();
    }
    float mu = sRed[0] / (float)L;
    __syncthreads();
    float d0 = sX[tid] - mu, d1 = sX[tid + 256] - mu;
    sRed[tid] = d0 * d0 + d1 * d1;
    __syncthreads();
    for (int off = 128; off > 0; off >>= 1) {
        if (tid < off) sRed[tid] += sRed[tid + off];
        __syncthreads();
    }
    float var = sRed[0] / (float)L;
    float rstd = rsqrtf(var + 1e-5f);
    for (int r = 0; r < 2; ++r) {
        int l = tid + r * 256;
        out[b * L + l] = (sX[l] - mu) * rstd * ln_g[l] + ln_b[l];
    }
}

// ======================= cooperative mega kernel ===========================
struct SetupS { int cnt; int meta[CAP]; };
struct TableS { float w1[KH][H]; float rbf[BPB][56]; unsigned short ab[BPB][APAD]; };
struct PairS  { float part[4][H]; };
struct MlpS   { float at[H][MATB]; float gt[H][MATB]; float part[4][MATB][H]; };
struct HeadS  { float p[H]; float pw[4][H]; float g[H]; float p2[4][L]; float x[L]; float red[256]; };
union __align__(16) SharedU { SetupS su; TableS tb; PairS pr; MlpS ml; HeadS hd; };

// (256,2): R3 evidence says (256,4) caps VGPR at 64 (spill disaster); one
// band up should cap at 128, enough for the ~100-VGPR pair pipeline while
// guaranteeing >=2 blocks/CU residency for the cooperative launch.
__global__ void __launch_bounds__(256, 2) mega_k(
        const int* __restrict__ z, const float* __restrict__ pos,
        const float* __restrict__ emb,
        const float* __restrict__ fw1, const float* __restrict__ fb1,
        const float* __restrict__ fw2, const float* __restrict__ fb2,
        const float* __restrict__ aw1, const float* __restrict__ ab1,
        const float* __restrict__ aw2, const float* __restrict__ ab2,
        const float* __restrict__ pw1, const float* __restrict__ pb1,
        const float* __restrict__ pw2, const float* __restrict__ pb2,
        const float* __restrict__ ln_g, const float* __restrict__ ln_b,
        float* __restrict__ out,
        float* __restrict__ hbuf0, float* __restrict__ hbuf1,
        float* __restrict__ agg,
        __half* __restrict__ hhalf0, __half* __restrict__ hhalf1,
        __half* __restrict__ Wtb, int* __restrict__ meta,
        int* __restrict__ cnts, unsigned short* __restrict__ Bt) {
    cg::grid_group grid = cg::this_grid();
    __shared__ SharedU S;
    int tid = threadIdx.x;
    int wid = tid >> 6, lane = tid & 63;
    int c4 = lane * 4;

    // ---------------- Phase 0: setup --------------------------------------
    for (int item = blockIdx.x; item < N + NI * H; item += gridDim.x) {
        if (item >= N) {
            int blk = item - N;
            int l = blk / H, ch = blk % H;
            float v = fw2[((size_t)l * H + tid) * H + ch];
            Bt[((size_t)l * H + ch) * H + tid] = f2bf(v);
            if (tid == 0)
                Wtb[((size_t)l * TROWS + NBINS) * H + ch] = __float2half(0.f);
            continue;
        }
        int i = item;
        float v = emb[z[i] * H + tid];
        hbuf0[i * H + tid] = v;
        hhalf0[i * H + tid] = __float2half(v);

        if (tid == 0) S.su.cnt = 0;
        __syncthreads();
        float pix = pos[i * 3 + 0], piy = pos[i * 3 + 1], piz = pos[i * 3 + 2];
        const float invd = (float)NBINS / CUT;
        for (int r = 0; r < 4; ++r) {
            int j = tid + r * 256;
            float dx = pos[j * 3 + 0] - pix;
            float dy = pos[j * 3 + 1] - piy;
            float dz = pos[j * 3 + 2] - piz;
            float d = sqrtf(dx * dx + dy * dy + dz * dz);
            bool keep = (d < CUT && d > 1e-6f);
            unsigned long long mk = __ballot(keep);
            int base = 0;
            if (lane == 0) base = atomicAdd(&S.su.cnt, (int)__popcll(mk));
            base = __shfl(base, 0);
            if (keep) {
                int bin = (int)(d * invd);
                if (bin > NBINS - 1) bin = NBINS - 1;
                int off = (int)__popcll(mk & ((1ull << lane) - 1ull));
                S.su.meta[base + off] = j | (bin << 10);
            }
        }
        __syncthreads();
        int cnt = S.su.cnt;
        int pc = (cnt + 31) & ~31;
        for (int t = cnt + tid; t < pc; t += 256)
            S.su.meta[t] = i | (NBINS << 10);
        __syncthreads();
        for (int t = tid; t < pc; t += 256)
            meta[(size_t)i * CAP + t] = S.su.meta[t];
        if (tid == 0) cnts[i] = pc;
        __syncthreads();
    }
    __threadfence();
    grid.sync();

    // ---------------- Phase 1: filter tables ------------------------------
    for (int item = blockIdx.x; item < NI * (NBINS / BPB); item += gridDim.x) {
        int layer = item / (NBINS / BPB);
        int blk = item % (NBINS / BPB);
        int b0 = blk * BPB;
        int ub = wid * 4;
        const float* lfw1 = fw1 + layer * NG * H;
        __half* lWt = Wtb + (size_t)layer * TROWS * H;
        const float delta = CUT / (float)NBINS;

        for (int idx = tid; idx < BPB * NG; idx += 256) {
            int u = idx & 15, k = idx >> 4;
            float d = ((float)(b0 + u) + 0.5f) * delta;
            float t = d - (float)k * (CUT / 49.0f);
            S.tb.rbf[u][k] = expf(t * t * -200.0f);
        }
        float4 q48 = *(const float4*)(lfw1 + 48 * H + c4);
        float4 q49 = *(const float4*)(lfw1 + 49 * H + c4);

        float4 acc1[4];
        #pragma unroll
        for (int u = 0; u < 4; ++u) acc1[u] = make_float4(0.f, 0.f, 0.f, 0.f);
        #pragma unroll
        for (int hf = 0; hf < 2; ++hf) {
            int kb = hf * KH;
            if (hf) __syncthreads();
            for (int idx = tid; idx < KH * (H / 4); idx += 256) {
                int k = idx >> 6, c = (idx & 63) * 4;
                *(float4*)&S.tb.w1[k][c] = *(const float4*)(lfw1 + (kb + k) * H + c);
            }
            __syncthreads();
            for (int kq = 0; kq < KH / 4; ++kq) {
                int k = kq * 4;
                float4 r0 = *(const float4*)&S.tb.rbf[ub + 0][kb + k];
                float4 r1 = *(const float4*)&S.tb.rbf[ub + 1][kb + k];
                float4 r2 = *(const float4*)&S.tb.rbf[ub + 2][kb + k];
                float4 r3 = *(const float4*)&S.tb.rbf[ub + 3][kb + k];
                float4 q0 = *(const float4*)&S.tb.w1[k + 0][c4];
                float4 q1 = *(const float4*)&S.tb.w1[k + 1][c4];
                float4 q2 = *(const float4*)&S.tb.w1[k + 2][c4];
                float4 q3 = *(const float4*)&S.tb.w1[k + 3][c4];
                FMA4(acc1[0], r0.x, q0); FMA4(acc1[0], r0.y, q1);
                FMA4(acc1[0], r0.z, q2); FMA4(acc1[0], r0.w, q3);
                FMA4(acc1[1], r1.x, q0); FMA4(acc1[1], r1.y, q1);
                FMA4(acc1[1], r1.z, q2); FMA4(acc1[1], r1.w, q3);
                FMA4(acc1[2], r2.x, q0); FMA4(acc1[2], r2.y, q1);
                FMA4(acc1[2], r2.z, q2); FMA4(acc1[2], r2.w, q3);
                FMA4(acc1[3], r3.x, q0); FMA4(acc1[3], r3.y, q1);
                FMA4(acc1[3], r3.z, q2); FMA4(acc1[3], r3.w, q3);
            }
        }
        #pragma unroll
        for (int u = 0; u < 4; ++u) {
            FMA4(acc1[u], S.tb.rbf[ub + u][48], q48);
            FMA4(acc1[u], S.tb.rbf[ub + u][49], q49);
        }
        float4 b1 = *(const float4*)(fb1 + layer * H + c4);
        #pragma unroll
        for (int u = 0; u < 4; ++u) {
            ushort4 g;
            g.x = f2bf(gelu_f(acc1[u].x + b1.x));
            g.y = f2bf(gelu_f(acc1[u].y + b1.y));
            g.z = f2bf(gelu_f(acc1[u].z + b1.z));
            g.w = f2bf(gelu_f(acc1[u].w + b1.w));
            *(ushort4*)&S.tb.ab[ub + u][c4] = g;
        }
        __syncthreads();

        int m = lane & 15;
        int quad = lane >> 4;
        bf16x8 afr[8];
        #pragma unroll
        for (int c = 0; c < 8; ++c)
            afr[c] = *(const bf16x8*)&S.tb.ab[m][c * 32 + quad * 8];
        #pragma unroll
        for (int ct = 0; ct < 4; ++ct) {
            int chn = (wid * 4 + ct) * 16 + m;
            const bf16x8* Bv = (const bf16x8*)(Bt + ((size_t)layer * H + chn) * H);
            f32x4 acc = {0.f, 0.f, 0.f, 0.f};
            #pragma unroll
            for (int c = 0; c < 8; ++c)
                acc = __builtin_amdgcn_mfma_f32_16x16x32_bf16(afr[c], Bv[c * 4 + quad],
                                                              acc, 0, 0, 0);
            float bias = fb2[layer * H + chn];
            #pragma unroll
            for (int r = 0; r < 4; ++r) {
                int bin = b0 + quad * 4 + r;
                lWt[(size_t)bin * H + chn] = __float2half(acc[r] + bias);
            }
        }
        __syncthreads();
    }
    __threadfence();
    grid.sync();

    // ---------------- NI x (pair -> mlp) ----------------------------------
    const float* hi = hbuf0;  float* ho = hbuf1;
    const __half* hfi = hhalf0; __half* hfo = hhalf1;
    for (int itn = 0; itn < NI; ++itn) {
        const __half* Wt = Wtb + (size_t)itn * TROWS * H;
        const float* aw1i = aw1 + itn * H * H;
        const float* ab1i = ab1 + itn * H;
        const float* aw2i = aw2 + itn * H * H;
        const float* ab2i = ab2 + itn * H;

        for (int i = blockIdx.x; i < N; i += gridDim.x) {
            int pc = cnts[i];
            int len = pc >> 2;
            int chunks = len >> 2;
            int sbase = __builtin_amdgcn_readfirstlane(wid * len);
            const int* mptr = meta + (size_t)i * CAP + sbase;
            const char* WtB = (const char*)Wt;
            const char* hhB = (const char*)hfi;
            int choffB = lane * 8;

            float4 acc = make_float4(0.f, 0.f, 0.f, 0.f);
            int4 mA, mB;
            uint2 wA[4], hA[4], wB[4], hB[4];

            auto ldmeta = [&](int c) -> int4 {
                return *(const int4*)(mptr + c * 4);
            };
            auto one = [&](int p, uint2& wr, uint2& hr) {
                p = __builtin_amdgcn_readfirstlane(p);
                int j = p & 1023;
                int bin = p >> 10;
                wr = *(const uint2*)(WtB + (((unsigned)bin << 9) | (unsigned)choffB));
                hr = *(const uint2*)(hhB + (((unsigned)j << 9) | (unsigned)choffB));
            };
            auto issueD = [&](const int4& m4, uint2 (&wr)[4], uint2 (&hr)[4]) {
                one(m4.x, wr[0], hr[0]); one(m4.y, wr[1], hr[1]);
                one(m4.z, wr[2], hr[2]); one(m4.w, wr[3], hr[3]);
            };
            auto consume = [&](uint2 (&wr)[4], uint2 (&hr)[4]) {
                #pragma unroll
                for (int u = 0; u < 4; ++u) {
                    __half2 w01 = *(__half2*)&wr[u].x;
                    __half2 w23 = *(__half2*)&wr[u].y;
                    __half2 h01 = *(__half2*)&hr[u].x;
                    __half2 h23 = *(__half2*)&hr[u].y;
                    acc.x += __half2float(w01.x) * __half2float(h01.x);
                    acc.y += __half2float(w01.y) * __half2float(h01.y);
                    acc.z += __half2float(w23.x) * __half2float(h23.x);
                    acc.w += __half2float(w23.y) * __half2float(h23.y);
                }
            };

            if (chunks > 0) {
                mA = ldmeta(0);
                if (chunks > 1) mB = ldmeta(1);
                issueD(mA, wA, hA);
                for (int c = 0; c < chunks; c += 2) {
                    if (c + 2 < chunks) mA = ldmeta(c + 2);
                    if (c + 1 < chunks) issueD(mB, wB, hB);
                    consume(wA, hA);
                    if (c + 3 < chunks) mB = ldmeta(c + 3);
                    if (c + 2 < chunks) issueD(mA, wA, hA);
                    if (c + 1 < chunks) consume(wB, hB);
                }
            }
            *(float4*)&S.pr.part[wid][c4] = acc;
            __syncthreads();
            agg[(size_t)i * H + tid] = S.pr.part[0][tid] + S.pr.part[1][tid]
                                     + S.pr.part[2][tid] + S.pr.part[3][tid];
            __syncthreads();
        }
        __threadfence();
        grid.sync();

        for (int it2 = blockIdx.x; it2 < N / MATB; it2 += gridDim.x) {
            int i0 = it2 * MATB;
            #pragma unroll
            for (int r = 0; r < MATB; ++r)
                S.ml.at[tid][r] = agg[(size_t)(i0 + r) * H + tid];
            __syncthreads();

            int k0 = wid * 64;
            float4 acc[MATB];
            #pragma unroll
            for (int a = 0; a < MATB; ++a) acc[a] = make_float4(0.f, 0.f, 0.f, 0.f);
            #pragma unroll 8
            for (int k = 0; k < 64; ++k) {
                float4 q = *(const float4*)(aw1i + (k0 + k) * H + c4);
                float4 act = *(const float4*)&S.ml.at[k0 + k][0];
                FMA4(acc[0], act.x, q); FMA4(acc[1], act.y, q);
                FMA4(acc[2], act.z, q); FMA4(acc[3], act.w, q);
            }
            #pragma unroll
            for (int a = 0; a < MATB; ++a)
                *(float4*)&S.ml.part[wid][a][c4] = acc[a];
            __syncthreads();
            {
                float b1v = ab1i[tid];
                float g[MATB];
                #pragma unroll
                for (int a = 0; a < MATB; ++a) {
                    float v = b1v;
                    #pragma unroll
                    for (int s = 0; s < 4; ++s) v += S.ml.part[s][a][tid];
                    g[a] = gelu_f(v);
                }
                *(float4*)&S.ml.gt[tid][0] = make_float4(g[0], g[1], g[2], g[3]);
            }
            __syncthreads();
            #pragma unroll
            for (int a = 0; a < MATB; ++a) acc[a] = make_float4(0.f, 0.f, 0.f, 0.f);
            #pragma unroll 8
            for (int k = 0; k < 64; ++k) {
                float4 q = *(const float4*)(aw2i + (k0 + k) * H + c4);
                float4 act = *(const float4*)&S.ml.gt[k0 + k][0];
                FMA4(acc[0], act.x, q); FMA4(acc[1], act.y, q);
                FMA4(acc[2], act.z, q); FMA4(acc[3], act.w, q);
            }
            #pragma unroll
            for (int a = 0; a < MATB; ++a)
                *(float4*)&S.ml.part[wid][a][c4] = acc[a];
            __syncthreads();
            {
                float b2v = ab2i[tid];
                #pragma unroll
                for (int a = 0; a < MATB; ++a) {
                    float v = b2v;
                    #pragma unroll
                    for (int s = 0; s < 4; ++s) v += S.ml.part[s][a][tid];
                    float hv = hi[(size_t)(i0 + a) * H + tid] + v;
                    ho[(size_t)(i0 + a) * H + tid] = hv;
                    hfo[(size_t)(i0 + a) * H + tid] = __float2half(hv);
                }
            }
            __syncthreads();
        }
        __threadfence();
        grid.sync();

        const float* t1 = hi; hi = ho; ho = (float*)t1;
        const __half* t2 = hfi; hfi = hfo; hfo = (__half*)t2;
    }

    // ---------------- head ------------------------------------------------
    for (int b = blockIdx.x; b < B; b += gridDim.x) {
        float4 p = make_float4(0.f, 0.f, 0.f, 0.f);
        #pragma unroll 4
        for (int a = 0; a < 16; ++a) {
            float4 hv = *(const float4*)(hi + (size_t)(b * 64 + wid * 16 + a) * H + c4);
            p.x += hv.x; p.y += hv.y; p.z += hv.z; p.w += hv.w;
        }
        *(float4*)&S.hd.pw[wid][c4] = p;
        __syncthreads();
        S.hd.p[tid] = S.hd.pw[0][tid] + S.hd.pw[1][tid] + S.hd.pw[2][tid] + S.hd.pw[3][tid];
        __syncthreads();

        int k0 = wid * 64;
        float4 acc = make_float4(0.f, 0.f, 0.f, 0.f);
        #pragma unroll 8
        for (int k = 0; k < 64; ++k) {
            float4 q = *(const float4*)(pw1 + (k0 + k) * H + c4);
            float s = S.hd.p[k0 + k];
            FMA4(acc, s, q);
        }
        *(float4*)&S.hd.pw[wid][c4] = acc;
        __syncthreads();
        S.hd.g[tid] = gelu_f(pb1[tid] + S.hd.pw[0][tid] + S.hd.pw[1][tid]
                             + S.hd.pw[2][tid] + S.hd.pw[3][tid]);
        __syncthreads();

        float4 a0 = make_float4(0.f, 0.f, 0.f, 0.f);
        float4 a1 = make_float4(0.f, 0.f, 0.f, 0.f);
        #pragma unroll 4
        for (int k = 0; k < 64; ++k) {
            float s = S.hd.g[k0 + k];
            float4 q0 = *(const float4*)(pw2 + (k0 + k) * L + lane * 8);
            float4 q1 = *(const float4*)(pw2 + (k0 + k) * L + lane * 8 + 4);
            FMA4(a0, s, q0);
            FMA4(a1, s, q1);
        }
        *(float4*)&S.hd.p2[wid][lane * 8] = a0;
        *(float4*)&S.hd.p2[wid][lane * 8 + 4] = a1;
        __syncthreads();
        for (int r = 0; r < 2; ++r) {
            int l = tid + r * 256;
            S.hd.x[l] = pb2[l] + S.hd.p2[0][l] + S.hd.p2[1][l]
                      + S.hd.p2[2][l] + S.hd.p2[3][l];
        }
        __syncthreads();

        S.hd.red[tid] = S.hd.x[tid] + S.hd.x[tid + 256];
        __syncthreads();
        for (int off = 128; off > 0; off >>= 1) {
            if (tid < off) S.hd.red[tid] += S.hd.red[tid + off];
            __syncthreads();
        }
        float mu = S.hd.red[0] / (float)L;
        __syncthreads();
        float d0 = S.hd.x[tid] - mu, d1 = S.hd.x[tid + 256] - mu;
        S.hd.red[tid] = d0 * d0 + d1 * d1;
        __syncthreads();
        for (int off = 128; off > 0; off >>= 1) {
            if (tid < off) S.hd.red[tid] += S.hd.red[tid + off];
            __syncthreads();
        }
        float var = S.hd.red[0] / (float)L;
        float rstd = rsqrtf(var + 1e-5f);
        for (int r = 0; r < 2; ++r) {
            int l = tid + r * 256;
            out[b * L + l] = (S.hd.x[l] - mu) * rstd * ln_g[l] + ln_b[l];
        }
        __syncthreads();
    }
}

extern "C" void kernel_launch(void* const* d_in, const int* in_sizes, int n_in,
                              void* d_out, int out_size, void* d_ws, size_t ws_size,
                              hipStream_t stream) {
    const int*   z    = (const int*)d_in[0];
    const float* pos  = (const float*)d_in[1];
    const float* emb  = (const float*)d_in[3];
    const float* fw1  = (const float*)d_in[4];
    const float* fb1  = (const float*)d_in[5];
    const float* fw2  = (const float*)d_in[6];
    const float* fb2  = (const float*)d_in[7];
    const float* aw1  = (const float*)d_in[8];
    const float* ab1  = (const float*)d_in[9];
    const float* aw2  = (const float*)d_in[10];
    const float* ab2  = (const float*)d_in[11];
    const float* pw1  = (const float*)d_in[12];
    const float* pb1  = (const float*)d_in[13];
    const float* pw2  = (const float*)d_in[14];
    const float* pb2  = (const float*)d_in[15];
    const float* ln_g = (const float*)d_in[16];
    const float* ln_b = (const float*)d_in[17];
    float* out = (float*)d_out;

    float* hbuf0 = (float*)d_ws;                        // [N][H] fp32
    float* hbuf1 = hbuf0 + N * H;                       // [N][H] fp32
    float* agg   = hbuf1 + N * H;                       // [2][N][H] region
    __half* hhalf0 = (__half*)(agg + 2 * N * H);        // [N][H] fp16
    __half* hhalf1 = hhalf0 + N * H;                    // [N][H] fp16
    __half* Wtb  = hhalf1 + N * H;                      // [NI][TROWS][H] fp16
    int* meta = (int*)(Wtb + (size_t)NI * TROWS * H);   // [N][CAP]
    int* cnts = meta + (size_t)N * CAP;                 // [N]
    unsigned short* Bt = (unsigned short*)(cnts + N);   // [NI][H][H] bf16

    // Cooperative path: grid sized to the compiler-guaranteed residency.
    static int occ = -1;
    if (occ < 0) {
        int q = 0;
        if (hipOccupancyMaxActiveBlocksPerMultiprocessor(&q, mega_k, 256, 0)
                != hipSuccess || q < 1)
            q = 2;                                      // (256,2) guarantees 2
        if (q > 4) q = 4;
        occ = q;
    }
    int nblk = occ * 256;
    if (nblk > 1024) nblk = 1024;

    void* args[] = { &z, &pos, &emb, &fw1, &fb1, &fw2, &fb2, &aw1, &ab1,
                     &aw2, &ab2, &pw1, &pb1, &pw2, &pb2, &ln_g, &ln_b, &out,
                     &hbuf0, &hbuf1, &agg, &hhalf0, &hhalf1, &Wtb, &meta,
                     &cnts, &Bt };
    hipError_t e = hipLaunchCooperativeKernel(mega_k, dim3(nblk), dim3(256),
                                              args, 0, stream);
    if (e != hipSuccess) {
        (void)hipGetLastError();                        // clear sticky error
        // Fallback: proven split-kernel sequence (R2, 233 us).
        setup_k<<<N + NI * H, 256, 0, stream>>>(z, emb, pos, hbuf0, hhalf0,
                                                meta, cnts, fw2, Bt, Wtb);
        table_k<<<NI * (NBINS / BPB), 256, 0, stream>>>(fw1, fb1, Bt, fb2, Wtb);
        float* hin = hbuf0;  __half* hbin = hhalf0;
        float* hout = hbuf1; __half* hbout = hhalf1;
        for (int it = 0; it < NI; ++it) {
            pair_k<<<2 * N, 256, 0, stream>>>(hbin, Wtb + (size_t)it * TROWS * H,
                                              meta, cnts, agg);
            mlp_k<<<N / MATB, 512, 0, stream>>>(agg, hin, aw1 + it * H * H,
                                                ab1 + it * H, aw2 + it * H * H,
                                                ab2 + it * H, hout, hbout);
            float* t1 = hin; hin = hout; hout = t1;
            __half* t2 = hbin; hbin = hbout; hbout = t2;
        }
        head_k<<<B, 256, 0, stream>>>(hin, pw1, pb1, pw2, pb2, ln_g, ln_b, out);
    }
}

// Round 6
// 243.274 us; speedup vs baseline: 5.1206x; 2.8957x over previous
//
#include <hip/hip_runtime.h>
#include <hip/hip_fp16.h>
#include <math.h>

#define N 1024
#define H 256
#define L 512
#define NG 50
#define NI 3
#define B 16
#define NBINS 2048         // nearest-bin LUT over [0, CUT], sampled at centers
#define CUT 5.0f
#define BPB 16             // bins per block in table_k (4 per wave, 1 MFMA tile)
#define TROWS (NBINS + 1)  // rows per table; row NBINS = zero sentinel
#define MATB 4             // atoms per block in mlp_k
#define CAP 768            // max (padded) neighbors per atom
#define SEGSZ 256          // neighbors per pair work-item (CAP/SEGSZ = 3 segs)
#define APAD 264           // padded LDS row (bf16) to break bank conflicts

typedef __attribute__((ext_vector_type(8))) short bf16x8;
typedef __attribute__((ext_vector_type(4))) float f32x4;

// NOTE: param must NOT be named 'w' — it would capture the '.w' member token.
#define FMA4(A_, S_, V_) do { \
    (A_).x = fmaf((S_), (V_).x, (A_).x); (A_).y = fmaf((S_), (V_).y, (A_).y); \
    (A_).z = fmaf((S_), (V_).z, (A_).z); (A_).w = fmaf((S_), (V_).w, (A_).w); } while (0)

__device__ __forceinline__ float gelu_f(float x) {
    return 0.5f * x * (1.0f + erff(x * 0.70710678118654752f));
}
__device__ __forceinline__ unsigned short f2bf(float f) {
    unsigned u = __float_as_uint(f);
    unsigned r = (u + 0x7fffu + ((u >> 16) & 1u)) >> 16;   // RNE
    return (unsigned short)r;
}

// Fused setup: blocks [0,N) = embed + neighbor list + agg zero; blocks
// [N, N+NI*H) = fw2 transpose (Bt) + sentinel-row zeroing.
__global__ void __launch_bounds__(256) setup_k(
        const int* __restrict__ z, const float* __restrict__ emb,
        const float* __restrict__ pos, float* __restrict__ h,
        __half* __restrict__ hhf, int* __restrict__ meta,
        int* __restrict__ cnts, const float* __restrict__ fw2,
        unsigned short* __restrict__ Bt, __half* __restrict__ Wtb,
        float* __restrict__ agg) {
    int tid = threadIdx.x;
    if (blockIdx.x >= N) {
        int blk = blockIdx.x - N;
        int l = blk / H, ch = blk % H;
        float v = fw2[((size_t)l * H + tid) * H + ch];
        Bt[((size_t)l * H + ch) * H + tid] = f2bf(v);
        if (tid == 0)
            Wtb[((size_t)l * TROWS + NBINS) * H + ch] = __float2half(0.f);
        return;
    }
    int i = blockIdx.x;
    float v = emb[z[i] * H + tid];
    h[i * H + tid] = v;
    hhf[i * H + tid] = __float2half(v);
    agg[(size_t)i * H + tid] = 0.f;        // pair phase accumulates atomically

    __shared__ int sCnt;
    __shared__ int sMeta[CAP];
    if (tid == 0) sCnt = 0;
    __syncthreads();
    float pix = pos[i * 3 + 0], piy = pos[i * 3 + 1], piz = pos[i * 3 + 2];
    const float invd = (float)NBINS / CUT;
    int lane = tid & 63;
    for (int r = 0; r < 4; ++r) {
        int j = tid + r * 256;
        float dx = pos[j * 3 + 0] - pix;
        float dy = pos[j * 3 + 1] - piy;
        float dz = pos[j * 3 + 2] - piz;
        float d = sqrtf(dx * dx + dy * dy + dz * dz);
        bool keep = (d < CUT && d > 1e-6f);
        unsigned long long mk = __ballot(keep);
        int base = 0;
        if (lane == 0) base = atomicAdd(&sCnt, (int)__popcll(mk));
        base = __shfl(base, 0);
        if (keep) {
            int bin = (int)(d * invd);
            if (bin > NBINS - 1) bin = NBINS - 1;
            int off = (int)__popcll(mk & ((1ull << lane) - 1ull));
            sMeta[base + off] = j | (bin << 10);
        }
    }
    __syncthreads();
    int cnt = sCnt;
    int pc = (cnt + 31) & ~31;             // mult of 32 -> seg lens mult of 32
    for (int t = cnt + tid; t < pc; t += 256)
        sMeta[t] = i | (NBINS << 10);      // sentinel -> zero row
    __syncthreads();
    for (int t = tid; t < pc; t += 256)
        meta[(size_t)i * CAP + t] = sMeta[t];
    if (tid == 0) cnts[i] = pc;
}

// Build all NI tables (fp16 out, sampled at bin CENTERS). grid = NI*128.
__global__ void __launch_bounds__(256) table_k(
        const float* __restrict__ fw1, const float* __restrict__ fb1,
        const unsigned short* __restrict__ Bt, const float* __restrict__ fb2,
        __half* __restrict__ Wtb) {
    const int bpl = NBINS / BPB;                  // 128 blocks per layer
    int layer = blockIdx.x / bpl;
    int blk = blockIdx.x % bpl;
    int b0 = blk * BPB;
    int tid = threadIdx.x;
    int wid = tid >> 6, lane = tid & 63;
    int c4 = lane * 4;
    int ub = wid * 4;
    const float* lfw1 = fw1 + layer * NG * H;
    __half* lWt = Wtb + (size_t)layer * TROWS * H;

    __shared__ __align__(16) float sW1[NG][H];
    __shared__ __align__(16) float sRbf[BPB][56];
    __shared__ __align__(16) unsigned short sAb[BPB][APAD];
    const float delta = CUT / (float)NBINS;
    for (int idx = tid; idx < NG * (H / 4); idx += 256) {
        int k = idx >> 6;
        int c = (idx & 63) * 4;
        *(float4*)&sW1[k][c] = *(const float4*)(lfw1 + k * H + c);
    }
    for (int idx = tid; idx < BPB * NG; idx += 256) {
        int u = idx & 15;
        int k = idx >> 4;
        float d = ((float)(b0 + u) + 0.5f) * delta;   // bin CENTER
        float t = d - (float)k * (CUT / 49.0f);
        sRbf[u][k] = expf(t * t * -200.0f);           // -1/(2*0.05^2)
    }
    __syncthreads();

    float4 acc1[4];
    #pragma unroll
    for (int u = 0; u < 4; ++u) acc1[u] = make_float4(0.f, 0.f, 0.f, 0.f);
    for (int kq = 0; kq < 12; ++kq) {
        int k = kq * 4;
        float4 r0 = *(const float4*)&sRbf[ub + 0][k];
        float4 r1 = *(const float4*)&sRbf[ub + 1][k];
        float4 r2 = *(const float4*)&sRbf[ub + 2][k];
        float4 r3 = *(const float4*)&sRbf[ub + 3][k];
        float4 q0 = *(const float4*)&sW1[k + 0][c4];
        float4 q1 = *(const float4*)&sW1[k + 1][c4];
        float4 q2 = *(const float4*)&sW1[k + 2][c4];
        float4 q3 = *(const float4*)&sW1[k + 3][c4];
        FMA4(acc1[0], r0.x, q0); FMA4(acc1[0], r0.y, q1);
        FMA4(acc1[0], r0.z, q2); FMA4(acc1[0], r0.w, q3);
        FMA4(acc1[1], r1.x, q0); FMA4(acc1[1], r1.y, q1);
        FMA4(acc1[1], r1.z, q2); FMA4(acc1[1], r1.w, q3);
        FMA4(acc1[2], r2.x, q0); FMA4(acc1[2], r2.y, q1);
        FMA4(acc1[2], r2.z, q2); FMA4(acc1[2], r2.w, q3);
        FMA4(acc1[3], r3.x, q0); FMA4(acc1[3], r3.y, q1);
        FMA4(acc1[3], r3.z, q2); FMA4(acc1[3], r3.w, q3);
    }
    for (int k = 48; k < NG; ++k) {
        float4 q = *(const float4*)&sW1[k][c4];
        #pragma unroll
        for (int u = 0; u < 4; ++u) FMA4(acc1[u], sRbf[ub + u][k], q);
    }
    float4 b1 = *(const float4*)(fb1 + layer * H + c4);
    #pragma unroll
    for (int u = 0; u < 4; ++u) {
        ushort4 g;
        g.x = f2bf(gelu_f(acc1[u].x + b1.x));
        g.y = f2bf(gelu_f(acc1[u].y + b1.y));
        g.z = f2bf(gelu_f(acc1[u].z + b1.z));
        g.w = f2bf(gelu_f(acc1[u].w + b1.w));
        *(ushort4*)&sAb[ub + u][c4] = g;
    }
    __syncthreads();

    int m = lane & 15;
    int quad = lane >> 4;
    bf16x8 afr[8];
    #pragma unroll
    for (int c = 0; c < 8; ++c)
        afr[c] = *(const bf16x8*)&sAb[m][c * 32 + quad * 8];
    #pragma unroll
    for (int ct = 0; ct < 4; ++ct) {
        int chn = (wid * 4 + ct) * 16 + m;
        const bf16x8* Bv = (const bf16x8*)(Bt + ((size_t)layer * H + chn) * H);
        f32x4 acc = {0.f, 0.f, 0.f, 0.f};
        #pragma unroll
        for (int c = 0; c < 8; ++c)
            acc = __builtin_amdgcn_mfma_f32_16x16x32_bf16(afr[c], Bv[c * 4 + quad],
                                                          acc, 0, 0, 0);
        float bias = fb2[layer * H + chn];
        #pragma unroll
        for (int r = 0; r < 4; ++r) {
            int bin = b0 + quad * 4 + r;
            lWt[(size_t)bin * H + chn] = __float2half(acc[r] + bias);
        }
    }
}

// Aggregation v3: work-balanced. Work item = (atom, 256-nbr segment); grid
// = 3N; blocks with an empty segment exit immediately. Every live block does
// <=64 nbrs/wave -> uniform block time, no straggler tail (R5 post-mortem:
// pair wall time was max-block, ~2x mean, because per-atom work varies 100-550
// nbrs). Partials land in agg via one fp32 atomicAdd per thread. agg is
// zeroed by setup_k (iter 0) and re-zeroed by mlp_k (iters 1,2).
// Scalar-meta inner loop (R2): uniform s_load meta, saddr W/h rows, ~5 VALU
// per neighbor. NO launch bound beyond 256 (R10/R3: reg caps -> spills).
__global__ void __launch_bounds__(256) pair_k(
    const __half* __restrict__ hhf, const __half* __restrict__ Wt,
    const int* __restrict__ gmeta, const int* __restrict__ cnts,
    float* __restrict__ agg) {
    int tid = threadIdx.x;
    int wid = tid >> 6, lane = tid & 63;
    int c4 = lane * 4;
    int b = blockIdx.x;
    int i = b / 3;                         // atom
    int seg = b - i * 3;                   // 0..2
    int pc = cnts[i];                      // padded count (multiple of 32)
    int sb = seg * SEGSZ;
    if (sb >= pc) return;                  // empty segment -> free the CU
    int rem = pc - sb; if (rem > SEGSZ) rem = SEGSZ;   // mult of 32
    int len = rem >> 2;                    // per-wave, multiple of 8
    int chunks = len >> 2;                 // 4-nbr chunks, even

    __shared__ __align__(16) float sPart[4][H];

    int sbase = __builtin_amdgcn_readfirstlane(sb + wid * len);
    const int* mptr = gmeta + (size_t)i * CAP + sbase;
    const char* WtB = (const char*)Wt;
    const char* hhB = (const char*)hhf;
    int choffB = lane * 8;                 // 4 fp16 = 8 B per lane

    float4 acc = make_float4(0.f, 0.f, 0.f, 0.f);
    int4 mA, mB;
    uint2 wA[4], hA[4], wB[4], hB[4];

    auto ldmeta = [&](int c) -> int4 {
        return *(const int4*)(mptr + c * 4);      // uniform addr -> s_load
    };
    auto one = [&](int p, uint2& wr, uint2& hr) {
        p = __builtin_amdgcn_readfirstlane(p);
        int j = p & 1023;
        int bin = p >> 10;
        wr = *(const uint2*)(WtB + (((unsigned)bin << 9) | (unsigned)choffB));
        hr = *(const uint2*)(hhB + (((unsigned)j << 9) | (unsigned)choffB));
    };
    auto issueD = [&](const int4& m4, uint2 (&wr)[4], uint2 (&hr)[4]) {
        one(m4.x, wr[0], hr[0]); one(m4.y, wr[1], hr[1]);
        one(m4.z, wr[2], hr[2]); one(m4.w, wr[3], hr[3]);
    };
    auto consume = [&](uint2 (&wr)[4], uint2 (&hr)[4]) {
        #pragma unroll
        for (int u = 0; u < 4; ++u) {
            __half2 w01 = *(__half2*)&wr[u].x;
            __half2 w23 = *(__half2*)&wr[u].y;
            __half2 h01 = *(__half2*)&hr[u].x;
            __half2 h23 = *(__half2*)&hr[u].y;
            acc.x += __half2float(w01.x) * __half2float(h01.x);  // v_fma_mix_f32
            acc.y += __half2float(w01.y) * __half2float(h01.y);
            acc.z += __half2float(w23.x) * __half2float(h23.x);
            acc.w += __half2float(w23.y) * __half2float(h23.y);
        }
    };

    if (chunks > 0) {
        mA = ldmeta(0);
        if (chunks > 1) mB = ldmeta(1);
        issueD(mA, wA, hA);
        for (int c = 0; c < chunks; c += 2) {
            if (c + 2 < chunks) mA = ldmeta(c + 2);
            if (c + 1 < chunks) issueD(mB, wB, hB);
            consume(wA, hA);
            if (c + 3 < chunks) mB = ldmeta(c + 3);
            if (c + 2 < chunks) issueD(mA, wA, hA);
            if (c + 1 < chunks) consume(wB, hB);
        }
    }
    *(float4*)&sPart[wid][c4] = acc;
    __syncthreads();
    float v = sPart[0][tid] + sPart[1][tid] + sPart[2][tid] + sPart[3][tid];
    atomicAdd(&agg[(size_t)i * H + tid], v);
}

// Atom MLP: hout = hin + gelu(agg@aw1+ab1)@aw2+ab2 (also emits fp16 mirror).
// Re-zeroes agg after reading it (next pair iteration accumulates atomically).
__global__ void __launch_bounds__(512) mlp_k(
    float* __restrict__ agg, const float* __restrict__ hin,
    const float* __restrict__ aw1, const float* __restrict__ ab1,
    const float* __restrict__ aw2, const float* __restrict__ ab2,
    float* __restrict__ hout, __half* __restrict__ hhf_out) {
    int tid = threadIdx.x;
    int wid = tid >> 6, lane = tid & 63;
    int c4 = lane * 4;
    int i0 = blockIdx.x * MATB;
    __shared__ __align__(16) float sAT[H][MATB];   // acts transposed [k][a]
    __shared__ __align__(16) float sGT[H][MATB];
    __shared__ __align__(16) float sPart[8][MATB][H];  // 32 KB

    if (tid < H) {
        #pragma unroll
        for (int r = 0; r < MATB; ++r) {
            sAT[tid][r] = agg[(size_t)(i0 + r) * H + tid];
            agg[(size_t)(i0 + r) * H + tid] = 0.f;     // ready for next iter
        }
    }
    __syncthreads();

    int k0 = wid * 32;
    float4 acc[MATB];
    #pragma unroll
    for (int a = 0; a < MATB; ++a) acc[a] = make_float4(0.f, 0.f, 0.f, 0.f);
    #pragma unroll 8
    for (int k = 0; k < 32; ++k) {
        float4 q = *(const float4*)(aw1 + (k0 + k) * H + c4);
        float4 act = *(const float4*)&sAT[k0 + k][0];
        FMA4(acc[0], act.x, q); FMA4(acc[1], act.y, q);
        FMA4(acc[2], act.z, q); FMA4(acc[3], act.w, q);
    }
    #pragma unroll
    for (int a = 0; a < MATB; ++a)
        *(float4*)&sPart[wid][a][c4] = acc[a];
    __syncthreads();
    if (tid < H) {
        float b1 = ab1[tid];
        float g[MATB];
        #pragma unroll
        for (int a = 0; a < MATB; ++a) {
            float v = b1;
            #pragma unroll
            for (int s = 0; s < 8; ++s) v += sPart[s][a][tid];
            g[a] = gelu_f(v);
        }
        *(float4*)&sGT[tid][0] = make_float4(g[0], g[1], g[2], g[3]);
    }
    __syncthreads();
    #pragma unroll
    for (int a = 0; a < MATB; ++a) acc[a] = make_float4(0.f, 0.f, 0.f, 0.f);
    #pragma unroll 8
    for (int k = 0; k < 32; ++k) {
        float4 q = *(const float4*)(aw2 + (k0 + k) * H + c4);
        float4 act = *(const float4*)&sGT[k0 + k][0];
        FMA4(acc[0], act.x, q); FMA4(acc[1], act.y, q);
        FMA4(acc[2], act.z, q); FMA4(acc[3], act.w, q);
    }
    #pragma unroll
    for (int a = 0; a < MATB; ++a)
        *(float4*)&sPart[wid][a][c4] = acc[a];
    __syncthreads();
    if (tid < H) {
        float b2 = ab2[tid];
        #pragma unroll
        for (int a = 0; a < MATB; ++a) {
            float v = b2;
            #pragma unroll
            for (int s = 0; s < 8; ++s) v += sPart[s][a][tid];
            float hv = hin[(i0 + a) * H + tid] + v;
            hout[(i0 + a) * H + tid] = hv;
            hhf_out[(i0 + a) * H + tid] = __float2half(hv);
        }
    }
}

// pooled -> gelu(pw1) -> pw2 -> layernorm. Block per molecule, waves split K.
__global__ void __launch_bounds__(256) head_k(
        const float* __restrict__ h,
        const float* __restrict__ pw1, const float* __restrict__ pb1,
        const float* __restrict__ pw2, const float* __restrict__ pb2,
        const float* __restrict__ ln_g, const float* __restrict__ ln_b,
        float* __restrict__ out) {
    int b = blockIdx.x, tid = threadIdx.x;
    int wid = tid >> 6, lane = tid & 63;
    int c4 = lane * 4;
    __shared__ float sP[H];
    __shared__ __align__(16) float sPw[4][H];
    __shared__ float sG[H];
    __shared__ __align__(16) float sP2[4][L];
    __shared__ float sX[L];
    __shared__ float sRed[256];

    float4 p = make_float4(0.f, 0.f, 0.f, 0.f);
    #pragma unroll 4
    for (int a = 0; a < 16; ++a) {
        float4 hv = *(const float4*)(h + (b * 64 + wid * 16 + a) * H + c4);
        p.x += hv.x; p.y += hv.y; p.z += hv.z; p.w += hv.w;
    }
    *(float4*)&sPw[wid][c4] = p;
    __syncthreads();
    sP[tid] = sPw[0][tid] + sPw[1][tid] + sPw[2][tid] + sPw[3][tid];
    __syncthreads();

    int k0 = wid * 64;
    float4 acc = make_float4(0.f, 0.f, 0.f, 0.f);
    #pragma unroll 8
    for (int k = 0; k < 64; ++k) {
        float4 q = *(const float4*)(pw1 + (k0 + k) * H + c4);
        float s = sP[k0 + k];
        FMA4(acc, s, q);
    }
    *(float4*)&sPw[wid][c4] = acc;
    __syncthreads();
    sG[tid] = gelu_f(pb1[tid] + sPw[0][tid] + sPw[1][tid] + sPw[2][tid] + sPw[3][tid]);
    __syncthreads();

    float4 a0 = make_float4(0.f, 0.f, 0.f, 0.f);
    float4 a1 = make_float4(0.f, 0.f, 0.f, 0.f);
    #pragma unroll 4
    for (int k = 0; k < 64; ++k) {
        float s = sG[k0 + k];
        float4 q0 = *(const float4*)(pw2 + (k0 + k) * L + lane * 8);
        float4 q1 = *(const float4*)(pw2 + (k0 + k) * L + lane * 8 + 4);
        FMA4(a0, s, q0);
        FMA4(a1, s, q1);
    }
    *(float4*)&sP2[wid][lane * 8] = a0;
    *(float4*)&sP2[wid][lane * 8 + 4] = a1;
    __syncthreads();
    for (int r = 0; r < 2; ++r) {
        int l = tid + r * 256;
        sX[l] = pb2[l] + sP2[0][l] + sP2[1][l] + sP2[2][l] + sP2[3][l];
    }
    __syncthreads();

    sRed[tid] = sX[tid] + sX[tid + 256];
    __syncthreads();
    for (int off = 128; off > 0; off >>= 1) {
        if (tid < off) sRed[tid] += sRed[tid + off];
        __syncthreads();
    }
    float mu = sRed[0] / (float)L;
    __syncthreads();
    float d0 = sX[tid] - mu, d1 = sX[tid + 256] - mu;
    sRed[tid] = d0 * d0 + d1 * d1;
    __syncthreads();
    for (int off = 128; off > 0; off >>= 1) {
        if (tid < off) sRed[tid] += sRed[tid + off];
        __syncthreads();
    }
    float var = sRed[0] / (float)L;
    float rstd = rsqrtf(var + 1e-5f);
    for (int r = 0; r < 2; ++r) {
        int l = tid + r * 256;
        out[b * L + l] = (sX[l] - mu) * rstd * ln_g[l] + ln_b[l];
    }
}

extern "C" void kernel_launch(void* const* d_in, const int* in_sizes, int n_in,
                              void* d_out, int out_size, void* d_ws, size_t ws_size,
                              hipStream_t stream) {
    const int*   z    = (const int*)d_in[0];
    const float* pos  = (const float*)d_in[1];
    // d_in[2] = batch: fixed arange//64 layout, handled implicitly in head_k
    const float* emb  = (const float*)d_in[3];
    const float* fw1  = (const float*)d_in[4];
    const float* fb1  = (const float*)d_in[5];
    const float* fw2  = (const float*)d_in[6];
    const float* fb2  = (const float*)d_in[7];
    const float* aw1  = (const float*)d_in[8];
    const float* ab1  = (const float*)d_in[9];
    const float* aw2  = (const float*)d_in[10];
    const float* ab2  = (const float*)d_in[11];
    const float* pw1  = (const float*)d_in[12];
    const float* pb1  = (const float*)d_in[13];
    const float* pw2  = (const float*)d_in[14];
    const float* pb2  = (const float*)d_in[15];
    const float* ln_g = (const float*)d_in[16];
    const float* ln_b = (const float*)d_in[17];
    float* out = (float*)d_out;

    float* hA  = (float*)d_ws;                        // [N][H] fp32
    float* hB  = hA + N * H;                          // [N][H] fp32
    float* agg = hB + N * H;                          // [N][H] fp32 (atomic)
    __half* hhfA = (__half*)(agg + 2 * N * H);        // [N][H] fp16
    __half* hhfB = hhfA + N * H;                      // [N][H] fp16
    __half* Wtb  = hhfB + N * H;                      // [NI][TROWS][H] fp16
    int* meta = (int*)(Wtb + (size_t)NI * TROWS * H); // [N][CAP]
    int* cnts = meta + (size_t)N * CAP;               // [N]
    unsigned short* Bt = (unsigned short*)(cnts + N); // [NI][H][H] bf16

    setup_k<<<N + NI * H, 256, 0, stream>>>(z, emb, pos, hA, hhfA, meta, cnts,
                                            fw2, Bt, Wtb, agg);
    table_k<<<NI * (NBINS / BPB), 256, 0, stream>>>(fw1, fb1, Bt, fb2, Wtb);
    float* hin = hA;  __half* hbin = hhfA;
    float* hout = hB; __half* hbout = hhfB;
    for (int it = 0; it < NI; ++it) {
        pair_k<<<3 * N, 256, 0, stream>>>(hbin, Wtb + (size_t)it * TROWS * H,
                                          meta, cnts, agg);
        mlp_k<<<N / MATB, 512, 0, stream>>>(agg, hin, aw1 + it * H * H, ab1 + it * H,
                                            aw2 + it * H * H, ab2 + it * H, hout, hbout);
        float* t1 = hin; hin = hout; hout = t1;
        __half* t2 = hbin; hbin = hbout; hbout = t2;
    }
    head_k<<<B, 256, 0, stream>>>(hin, pw1, pb1, pw2, pb2, ln_g, ln_b, out);
}